// Round 1
// baseline (208.855 us; speedup 1.0000x reference)
//
#include <hip/hip_runtime.h>

#define NN 4096
constexpr int TPB = 256;
constexpr int CPB = 1024;                  // columns per block (256 thr x 4)
constexpr int NSTRIP = NN / CPB;           // 4 column strips
constexpr int RPB = 16;                    // rows per block
constexpr int NROWG = NN / RPB;            // 256 row groups
constexpr int NRSLOT = NSTRIP * (TPB / 64);// 16 row-partial slots

__device__ __forceinline__ float sigmoidf_(float x) {
    return 1.0f / (1.0f + __expf(-x));
}

// d_f[i*N+j] = base_f[i][j][1] - base_f[i][j][0]; thread handles 4 pairs
__global__ void diff_kernel(const float4* __restrict__ bf, float4* __restrict__ df) {
    int t = blockIdx.x * blockDim.x + threadIdx.x;   // t < N*N/4
    float4 a = bf[2 * t];
    float4 b = bf[2 * t + 1];
    df[t] = make_float4(a.y - a.x, a.w - a.z, b.y - b.x, b.w - b.z);
}

// s1 = sigmoid(base_s[:,1] - base_s[:,0])
__global__ void init_s_kernel(const float2* __restrict__ bs, float* __restrict__ s1) {
    int x = blockIdx.x * blockDim.x + threadIdx.x;
    if (x < NN) {
        float2 v = bs[x];
        s1[x] = sigmoidf_(v.y - v.x);
    }
}

// Fused dual reduction over f1 = sigmoid(d - w*s1p[i]*s0p[j]).
// MODE 0: src is d_f (contiguous diffs). MODE 1: src is base_f interleaved.
// Row partials -> rowpart[slot][i], slot = strip*4 + wave (16 slots)
// Col partials -> colpart[rowgroup][j] (256 groups)
template <int MODE>
__global__ void step_kernel(const float* __restrict__ src,
                            const float* __restrict__ s1c,
                            const float* __restrict__ s1p,
                            const float* __restrict__ wptr, int first,
                            float* __restrict__ rowpart,
                            float* __restrict__ colpart) {
    const int t = threadIdx.x;
    const int strip = blockIdx.x & (NSTRIP - 1);
    const int rg = blockIdx.x / NSTRIP;
    const int j0 = strip * CPB + t * 4;
    const float w = first ? 0.0f : wptr[0];

    float s0cv[4], ws0p[4];
#pragma unroll
    for (int k = 0; k < 4; ++k) {
        s0cv[k] = 1.0f - s1c[j0 + k];
        ws0p[k] = w * (1.0f - s1p[j0 + k]);
    }

    float colacc[4] = {0.f, 0.f, 0.f, 0.f};
    const int i0 = rg * RPB;

#pragma unroll 4
    for (int r = 0; r < RPB; ++r) {
        const int i = i0 + r;
        const float s1ci = s1c[i];
        const float s1pi = s1p[i];
        float4 d;
        if (MODE == 0) {
            d = *reinterpret_cast<const float4*>(src + (size_t)i * NN + j0);
        } else {
            const float4* p =
                reinterpret_cast<const float4*>(src + ((size_t)i * NN + j0) * 2);
            float4 a = p[0], b = p[1];
            d = make_float4(a.y - a.x, a.w - a.z, b.y - b.x, b.w - b.z);
        }
        float dd[4] = {d.x, d.y, d.z, d.w};
        float rowp = 0.f;
#pragma unroll
        for (int k = 0; k < 4; ++k) {
            float x = dd[k] - s1pi * ws0p[k];
            float f1 = sigmoidf_(x);
            colacc[k] += s1ci * f1;
            rowp += f1 * s0cv[k];
        }
        // wave64 reduce
#pragma unroll
        for (int off = 32; off > 0; off >>= 1) rowp += __shfl_down(rowp, off);
        if ((t & 63) == 0) {
            rowpart[(size_t)(strip * (TPB / 64) + (t >> 6)) * NN + i] = rowp;
        }
    }
    *reinterpret_cast<float4*>(colpart + (size_t)rg * NN + j0) =
        make_float4(colacc[0], colacc[1], colacc[2], colacc[3]);
}

// Reduce partials, update s for next step; optionally write out_s (last step)
__global__ void update_kernel(const float* __restrict__ rowpart,
                              const float* __restrict__ colpart,
                              const float2* __restrict__ bs,
                              const float* __restrict__ wptr,
                              float* __restrict__ s1next,
                              float* __restrict__ out_s, int writeOut) {
    int x = blockIdx.x * blockDim.x + threadIdx.x;
    if (x >= NN) return;
    float m0 = 0.f;
#pragma unroll
    for (int s = 0; s < NRSLOT; ++s) m0 += rowpart[(size_t)s * NN + x];
    float m1 = 0.f;
    for (int g = 0; g < NROWG; ++g) m1 += colpart[(size_t)g * NN + x];
    float w = wptr[0];
    float2 b = bs[x];
    float c0 = b.x + w * m0;
    float c1 = b.y + w * m1;
    s1next[x] = sigmoidf_(c1 - c0);
    if (writeOut) {
        out_s[2 * x] = c0;
        out_s[2 * x + 1] = c1;
    }
}

// out_f[i][j][0] = base_f[i][j][0] + w*s1[i]*(1-s1[j]); channel 1 copied
__global__ void final_f_kernel(const float4* __restrict__ bf,
                               const float* __restrict__ s1f,
                               const float* __restrict__ wptr,
                               float4* __restrict__ of) {
    int idx = blockIdx.x * blockDim.x + threadIdx.x;  // idx < N*N/2 (2 pairs)
    int i = idx / (NN / 2);
    int jp = idx % (NN / 2);
    int j = 2 * jp;
    float w = wptr[0];
    float4 b = bf[idx];
    float a = w * s1f[i];
    float v0 = b.x + a * (1.0f - s1f[j]);
    float v1 = b.z + a * (1.0f - s1f[j + 1]);
    of[idx] = make_float4(v0, b.y, v1, b.w);
}

extern "C" void kernel_launch(void* const* d_in, const int* in_sizes, int n_in,
                              void* d_out, int out_size, void* d_ws,
                              size_t ws_size, hipStream_t stream) {
    const float* base_s = (const float*)d_in[0];   // (N,2)
    const float* base_f = (const float*)d_in[1];   // (N,N,2)
    const float* wptr = (const float*)d_in[2];     // (1,)
    float* out_s = (float*)d_out;                  // first 2N floats
    float* out_f = (float*)d_out + 2 * NN;         // then N*N*2 floats

    char* ws = (char*)d_ws;
    size_t off = 0;
    auto alloc = [&](size_t bytes) {
        void* p = ws + off;
        off = (off + bytes + 255) & ~(size_t)255;
        return p;
    };
    float* sA = (float*)alloc((size_t)NN * 4);
    float* sB = (float*)alloc((size_t)NN * 4);
    float* rowpart = (float*)alloc((size_t)NRSLOT * NN * 4);
    float* colpart = (float*)alloc((size_t)NROWG * NN * 4);
    float* df = (float*)(ws + off);
    bool use_df = (ws_size >= off + (size_t)NN * NN * 4);

    if (use_df) {
        diff_kernel<<<(NN * (size_t)NN / 4) / TPB, TPB, 0, stream>>>(
            (const float4*)base_f, (float4*)df);
    }
    init_s_kernel<<<NN / TPB, TPB, 0, stream>>>((const float2*)base_s, sA);

    float* cur = sA;
    float* prev = sA;  // unused at k=1 (w=0)
    float* nxt = sB;
    float* s_final = sA;

    for (int k = 1; k <= 5; ++k) {
        int first = (k == 1) ? 1 : 0;
        if (use_df) {
            step_kernel<0><<<NSTRIP * NROWG, TPB, 0, stream>>>(
                df, cur, prev, wptr, first, rowpart, colpart);
        } else {
            step_kernel<1><<<NSTRIP * NROWG, TPB, 0, stream>>>(
                base_f, cur, prev, wptr, first, rowpart, colpart);
        }
        update_kernel<<<NN / TPB, TPB, 0, stream>>>(
            rowpart, colpart, (const float2*)base_s, wptr, nxt, out_s,
            (k == 5) ? 1 : 0);
        if (k == 5) s_final = cur;
        float* old_cur = cur;
        cur = nxt;
        prev = old_cur;
        nxt = old_cur;  // ping-pong: new s overwrites the buffer no longer needed
    }

    final_f_kernel<<<(NN * (size_t)NN / 2) / TPB, TPB, 0, stream>>>(
        (const float4*)base_f, s_final, wptr, (float4*)out_f);
}